// Round 1
// baseline (1217.056 us; speedup 1.0000x reference)
//
#include <hip/hip_runtime.h>
#include <hip/hip_bf16.h>
#include <stdint.h>
#include <stddef.h>

#define N_NODES 100000
#define N_EDGES 1600000
#define FEAT 128
#define NB_SCAN ((N_NODES + 255) / 256)   // 391 blocks of 256 for the scan
#define LDS_PITCH 136                     // u16; 272 B/row = 2-way bank alias (free)
#define CAP 24                            // edges per gather chunk (6 loads in flight)
#define NL (CAP / 4)                      // gather loads in flight per chunk

typedef __attribute__((ext_vector_type(8))) short bf16x8;
typedef __attribute__((ext_vector_type(4))) float f32x4;
typedef unsigned short u16;

__device__ __forceinline__ float bf2f(u16 u) {
    union { unsigned int i; float f; } v; v.i = ((unsigned int)u) << 16; return v.f;
}
__device__ __forceinline__ u16 f2bf(float f) {
    union { float f; unsigned int i; } v; v.f = f;
    unsigned int x = v.i;
    return (u16)((x + 0x7fffu + ((x >> 16) & 1u)) >> 16);   // round-nearest-even
}

// ---------------- CSR build ----------------

__global__ void hist_kernel(const int* __restrict__ rows, int* __restrict__ counts) {
    int e = blockIdx.x * blockDim.x + threadIdx.x;
    if (e < N_EDGES) {
        int r = rows[e];
        r = min(max(r, 0), N_NODES - 1);
        atomicAdd(&counts[r], 1);
    }
}

__global__ void reduce_counts_kernel(const int* __restrict__ counts, int* __restrict__ bsum) {
    __shared__ int s[256];
    int i = blockIdx.x * 256 + threadIdx.x;
    int v = (i < N_NODES) ? counts[i] : 0;
    s[threadIdx.x] = v; __syncthreads();
    for (int off = 128; off > 0; off >>= 1) {
        if (threadIdx.x < off) s[threadIdx.x] += s[threadIdx.x + off];
        __syncthreads();
    }
    if (threadIdx.x == 0) bsum[blockIdx.x] = s[0];
}

__global__ void scan_bsums_kernel(int* __restrict__ bsum, int* __restrict__ row_ptr) {
    __shared__ int s[512];
    int t = threadIdx.x;
    int v = (t < NB_SCAN) ? bsum[t] : 0;
    s[t] = v; __syncthreads();
    for (int off = 1; off < 512; off <<= 1) {
        int x = (t >= off) ? s[t - off] : 0;
        __syncthreads();
        s[t] += x;
        __syncthreads();
    }
    if (t < NB_SCAN) bsum[t] = s[t] - v;              // exclusive
    if (t == NB_SCAN - 1) row_ptr[N_NODES] = s[t];    // total (= N_EDGES)
}

// also zeroes counts so it can be reused as the scatter fill array
__global__ void write_rowptr_kernel(int* __restrict__ counts, const int* __restrict__ bsum,
                                    int* __restrict__ row_ptr) {
    __shared__ int s[256];
    int i = blockIdx.x * 256 + threadIdx.x;
    int v = (i < N_NODES) ? counts[i] : 0;
    s[threadIdx.x] = v; __syncthreads();
    for (int off = 1; off < 256; off <<= 1) {
        int x = (threadIdx.x >= off) ? s[threadIdx.x - off] : 0;
        __syncthreads();
        s[threadIdx.x] += x;
        __syncthreads();
    }
    if (i < N_NODES) {
        row_ptr[i] = bsum[blockIdx.x] + s[threadIdx.x] - v;  // exclusive
        counts[i] = 0;                                       // becomes fill[]
    }
}

// pack (col, weight-bits) per sorted edge slot
__global__ void scatter_kernel(const int* __restrict__ rows, const int* __restrict__ cols,
                               const float* __restrict__ w, const int* __restrict__ row_ptr,
                               int* __restrict__ fill, int2* __restrict__ ecw) {
    int e = blockIdx.x * blockDim.x + threadIdx.x;
    if (e < N_EDGES) {
        int r = rows[e];
        r = min(max(r, 0), N_NODES - 1);
        int pos = row_ptr[r] + atomicAdd(&fill[r], 1);
        pos = min(max(pos, 0), N_EDGES - 1);
        int c = cols[e];
        c = min(max(c, 0), N_NODES - 1);
        ecw[pos] = make_int2(c, __float_as_int(w[e]));
    }
}

// -------- weight prep: W' = [W0-W2 | W1 | 2*W2], f32 -> bf16 ----------

__global__ void prep_w_kernel(const float* __restrict__ W, u16* __restrict__ Wp, int O) {
    int i = blockIdx.x * blockDim.x + threadIdx.x;
    if (i >= O * 384) return;
    int o = i / 384, k = i % 384;
    float v;
    if (k < 128)      v = W[o * 384 + k] - W[o * 384 + 256 + k];
    else if (k < 256) v = W[o * 384 + k];
    else              v = 2.0f * W[o * 384 + k];
    Wp[i] = f2bf(v);
}

// -------- x (f32) -> bf16, 4 elems per thread ----------

__global__ void cvt_kernel(const float* __restrict__ x, u16* __restrict__ y) {
    int i = blockIdx.x * blockDim.x + threadIdx.x;
    if (i >= N_NODES * FEAT / 4) return;
    float4 v = ((const float4*)x)[i];
    ushort4 o;
    o.x = f2bf(v.x); o.y = f2bf(v.y); o.z = f2bf(v.z); o.w = f2bf(v.w);
    ((ushort4*)y)[i] = o;
}

// -------- register-resident row gather -------------------------------------
// One wave computes one output row. Per chunk of <=CAP edges: one coalesced
// meta load, then NL=6 bf16x8 per-lane global loads issued back-to-back
// (6 KB in flight, incremental vmcnt waits inserted by the compiler), reduced
// straight from registers. No LDS staging, no vmcnt(0) drain.
// lane = g*16+f (g: edge slot in quad, f: feature group of 8). Result acc[8]
// is the full row sum, replicated across g after the shfl reduction.
// Chunk guards (n) are wave-uniform -> scalar branches, no divergence.

__device__ __forceinline__ void gather_one_row(const int2* __restrict__ ecw,
                                               const u16* __restrict__ X,
                                               int s, int e,
                                               int lane, int g, int f, float* acc) {
#pragma unroll
    for (int j = 0; j < 8; ++j) acc[j] = 0.f;
    for (int cs = s; cs < e; cs += CAP) {
        int n = min(e - cs, CAP);
        int2 cw = make_int2(0, 0);
        if (lane < n) cw = ecw[cs + lane];          // meta: one coalesced load/chunk
        int   call = cw.x;
        float wall = __int_as_float(cw.y);
        bf16x8 xq[NL];
#pragma unroll
        for (int k = 0; k < NL; ++k) {
            if (k * 4 < n) {                         // wave-uniform guard
                int col = __shfl(call, k * 4 + g);
                xq[k] = *(const bf16x8*)(X + (size_t)col * FEAT + f * 8);
            }
        }
#pragma unroll
        for (int k = 0; k < NL; ++k) {
            if (k * 4 < n) {
                float wj = __shfl(wall, k * 4 + g);
#pragma unroll
                for (int j = 0; j < 8; ++j) acc[j] += wj * bf2f((u16)xq[k][j]);
            }
        }
    }
#pragma unroll
    for (int j = 0; j < 8; ++j) {
        acc[j] += __shfl_xor(acc[j], 16);
        acc[j] += __shfl_xor(acc[j], 32);
    }
}

// -------- SpMM: Y[r,:] = sum_e w_e * X[col_e,:]  (4 rows per wave) --------

__global__ __launch_bounds__(256) void spmm_kernel(const int* __restrict__ row_ptr,
                                                   const int2* __restrict__ ecw,
                                                   const u16* __restrict__ X,
                                                   u16* __restrict__ Y) {
    int wid = threadIdx.x >> 6;
    int lane = threadIdx.x & 63;
    int g = lane >> 4, f = lane & 15;
    int r0 = blockIdx.x * 16 + wid * 4;                   // 16 rows/block

    for (int y = 0; y < 4; ++y) {
        int rr = r0 + y;
        int s = row_ptr[rr], e = row_ptr[rr + 1];
        float acc[8];
        gather_one_row(ecw, X, s, e, lane, g, f, acc);
        if (g == 0) {
            u16 tmp[8];
#pragma unroll
            for (int j = 0; j < 8; ++j) tmp[j] = f2bf(acc[j]);
            *(bf16x8*)(Y + (size_t)rr * FEAT + f * 8) = *(const bf16x8*)tmp;
        }
    }
}

// ------- fused: one block = one 16-row tile. Phase 1: 4 waves gather 4 s2
//         rows each into the shared sT tile. Phase 2: each wave computes O/64
//         column-tiles of out = act( H@W0' + T1@W1' + s2@W2' + b [+H] ).

template <int O, bool RELU, bool RES, bool OUT_F32>
__global__ __launch_bounds__(256) void fused_gemm_kernel(const int* __restrict__ row_ptr,
                                                         const int2* __restrict__ ecw,
                                                         const u16* __restrict__ H,
                                                         const u16* __restrict__ T1,
                                                         const u16* __restrict__ Wp,
                                                         const float* __restrict__ bias,
                                                         void* __restrict__ outv) {
    __shared__ __align__(16) u16 sT[16 * LDS_PITCH];      // 4.25 KB s2 tile
    int wid = threadIdx.x >> 6;
    int lane = threadIdx.x & 63;
    int g = lane >> 4, f = lane & 15;
    int m0 = blockIdx.x * 16;                             // N_NODES % 16 == 0

    // Phase 1: wave wid gathers s2 rows y = wid*4 .. wid*4+3
    for (int y = wid * 4; y < wid * 4 + 4; ++y) {
        int rr = m0 + y;
        int s = row_ptr[rr], e = row_ptr[rr + 1];
        float acc[8];
        gather_one_row(ecw, T1, s, e, lane, g, f, acc);
        if (g == 0) {
            u16 tmp[8];
#pragma unroll
            for (int j = 0; j < 8; ++j) tmp[j] = f2bf(acc[j]);
            *(bf16x8*)(sT + y * LDS_PITCH + f * 8) = *(const bf16x8*)tmp;
        }
    }
    __syncthreads();

    // Phase 2: MFMA over K = [H(128) | T1(128) | s2(128)]; wave wid owns
    // column-tiles t = wid*NW .. wid*NW+NW-1
    int r = f, q = g;
    constexpr int NT = O / 16;
    constexpr int NW = NT / 4;          // 2 for O=128, 1 for O=64
    f32x4 acc[NW];
#pragma unroll
    for (int t = 0; t < NW; ++t) acc[t] = (f32x4){0.f, 0.f, 0.f, 0.f};

#pragma unroll
    for (int kk = 0; kk < 12; ++kk) {
        bf16x8 af;
        if (kk < 4)
            af = *(const bf16x8*)(H + (size_t)(m0 + r) * FEAT + kk * 32 + q * 8);
        else if (kk < 8)
            af = *(const bf16x8*)(T1 + (size_t)(m0 + r) * FEAT + (kk - 4) * 32 + q * 8);
        else
            af = *(const bf16x8*)(sT + r * LDS_PITCH + (kk - 8) * 32 + q * 8);
#pragma unroll
        for (int t = 0; t < NW; ++t) {
            int ot = wid * NW + t;
            bf16x8 bfr = *(const bf16x8*)(Wp + (size_t)(ot * 16 + r) * 384 + kk * 32 + q * 8);
            acc[t] = __builtin_amdgcn_mfma_f32_16x16x32_bf16(af, bfr, acc[t], 0, 0, 0);
        }
    }

#pragma unroll
    for (int t = 0; t < NW; ++t) {
        int col = (wid * NW + t) * 16 + r;
        float bv = bias[col];
#pragma unroll
        for (int i = 0; i < 4; ++i) {
            int row = m0 + q * 4 + i;
            float v = acc[t][i] + bv;
            if (RES)  v += bf2f(H[(size_t)row * FEAT + col]);
            if (RELU) v = fmaxf(v, 0.f);
            if (OUT_F32) ((float*)outv)[(size_t)row * O + col] = v;
            else         ((u16*)outv)[(size_t)row * O + col] = f2bf(v);
        }
    }
}

// ---------------- launcher ----------------

static inline size_t align_up(size_t x) { return (x + 255) & ~(size_t)255; }

extern "C" void kernel_launch(void* const* d_in, const int* in_sizes, int n_in,
                              void* d_out, int out_size, void* d_ws, size_t ws_size,
                              hipStream_t stream) {
    const float* x     = (const float*)d_in[0];
    const int*   ei    = (const int*)d_in[1];
    const float* ew    = (const float*)d_in[2];
    const float* W_in  = (const float*)d_in[3];
    const float* b_in  = (const float*)d_in[4];
    const float* W_h1  = (const float*)d_in[5];
    const float* b_h1  = (const float*)d_in[6];
    const float* W_h2  = (const float*)d_in[7];
    const float* b_h2  = (const float*)d_in[8];
    const float* W_out = (const float*)d_in[9];
    const float* b_out = (const float*)d_in[10];

    const int* rows = ei;
    const int* cols = ei + N_EDGES;

    // workspace layout — ~65.2 MB (proven budget)
    char* w = (char*)d_ws;
    size_t off = 0;
    int* counts = (int*)(w + off);            off = align_up(off + (size_t)N_NODES * 4);   // reused as fill
    int* row_ptr= (int*)(w + off);            off = align_up(off + (size_t)(N_NODES + 1) * 4);
    int* bsum   = (int*)(w + off);            off = align_up(off + 512 * 4);
    int2* ecw   = (int2*)(w + off);           off = align_up(off + (size_t)N_EDGES * 8);
    u16* t1     = (u16*)(w + off);            off = align_up(off + (size_t)N_NODES * FEAT * 2);
    u16* h      = (u16*)(w + off);            off = align_up(off + (size_t)N_NODES * FEAT * 2);
    u16* Wp_in  = (u16*)(w + off);            off = align_up(off + (size_t)128 * 384 * 2);
    u16* Wp_h1  = (u16*)(w + off);            off = align_up(off + (size_t)128 * 384 * 2);
    u16* Wp_h2  = (u16*)(w + off);            off = align_up(off + (size_t)128 * 384 * 2);
    u16* Wp_out = (u16*)(w + off);            off = align_up(off + (size_t)64 * 384 * 2);

    hipMemsetAsync(counts, 0, (size_t)N_NODES * 4, stream);

    // weight prep + input conversion
    prep_w_kernel<<<(128 * 384 + 255) / 256, 256, 0, stream>>>(W_in, Wp_in, 128);
    prep_w_kernel<<<(128 * 384 + 255) / 256, 256, 0, stream>>>(W_h1, Wp_h1, 128);
    prep_w_kernel<<<(128 * 384 + 255) / 256, 256, 0, stream>>>(W_h2, Wp_h2, 128);
    prep_w_kernel<<<(64 * 384 + 255) / 256, 256, 0, stream>>>(W_out, Wp_out, 64);
    cvt_kernel<<<(N_NODES * FEAT / 4 + 255) / 256, 256, 0, stream>>>(x, h);

    // CSR build (counting sort)
    hist_kernel<<<N_EDGES / 256, 256, 0, stream>>>(rows, counts);
    reduce_counts_kernel<<<NB_SCAN, 256, 0, stream>>>(counts, bsum);
    scan_bsums_kernel<<<1, 512, 0, stream>>>(bsum, row_ptr);
    write_rowptr_kernel<<<NB_SCAN, 256, 0, stream>>>(counts, bsum, row_ptr);  // zeroes counts -> fill
    scatter_kernel<<<N_EDGES / 256, 256, 0, stream>>>(rows, cols, ew, row_ptr, counts, ecw);

    const int grid16 = N_NODES / 16;   // 6250 blocks: 16 rows per 256-thread block

    // Layer 1: h = relu(cheb(x))    (x pre-converted to bf16 in h; in-place row-local GEMM)
    spmm_kernel<<<grid16, 256, 0, stream>>>(row_ptr, ecw, h, t1);
    fused_gemm_kernel<128, true, false, false><<<grid16, 256, 0, stream>>>(
        row_ptr, ecw, h, t1, Wp_in, b_in, h);

    // Layer 2: h = relu(cheb(h) + h)
    spmm_kernel<<<grid16, 256, 0, stream>>>(row_ptr, ecw, h, t1);
    fused_gemm_kernel<128, true, true, false><<<grid16, 256, 0, stream>>>(
        row_ptr, ecw, h, t1, Wp_h1, b_h1, h);

    // Layer 3: h = relu(cheb(h) + h)
    spmm_kernel<<<grid16, 256, 0, stream>>>(row_ptr, ecw, h, t1);
    fused_gemm_kernel<128, true, true, false><<<grid16, 256, 0, stream>>>(
        row_ptr, ecw, h, t1, Wp_h2, b_h2, h);

    // Layer 4: out = cheb(h)   (O = 64, f32 output, no relu/residual)
    spmm_kernel<<<grid16, 256, 0, stream>>>(row_ptr, ecw, h, t1);
    fused_gemm_kernel<64, false, false, true><<<grid16, 256, 0, stream>>>(
        row_ptr, ecw, h, t1, Wp_out, b_out, d_out);
}

// Round 2
// 992.976 us; speedup vs baseline: 1.2257x; 1.2257x over previous
//
#include <hip/hip_runtime.h>
#include <hip/hip_bf16.h>
#include <stdint.h>
#include <stddef.h>

#define N_NODES 100000
#define N_EDGES 1600000
#define FEAT 128
#define NB_SCAN ((N_NODES + 255) / 256)   // 391 blocks of 256 for the scan
#define LDS_PITCH 136                     // u16; 272 B/row = 2-way bank alias (free)
#define CAP 24                            // edges per gather chunk
#define NL (CAP / 4)                      // 6 load instructions per chunk

typedef __attribute__((ext_vector_type(8))) short bf16x8;
typedef __attribute__((ext_vector_type(4))) float f32x4;
typedef unsigned short u16;

__device__ __forceinline__ float bf2f(u16 u) {
    union { unsigned int i; float f; } v; v.i = ((unsigned int)u) << 16; return v.f;
}
__device__ __forceinline__ u16 f2bf(float f) {
    union { float f; unsigned int i; } v; v.f = f;
    unsigned int x = v.i;
    return (u16)((x + 0x7fffu + ((x >> 16) & 1u)) >> 16);   // round-nearest-even
}

// ---------------- CSR build ----------------

__global__ void hist_kernel(const int* __restrict__ rows, int* __restrict__ counts) {
    int e = blockIdx.x * blockDim.x + threadIdx.x;
    if (e < N_EDGES) {
        int r = rows[e];
        r = min(max(r, 0), N_NODES - 1);
        atomicAdd(&counts[r], 1);
    }
}

__global__ void reduce_counts_kernel(const int* __restrict__ counts, int* __restrict__ bsum) {
    __shared__ int s[256];
    int i = blockIdx.x * 256 + threadIdx.x;
    int v = (i < N_NODES) ? counts[i] : 0;
    s[threadIdx.x] = v; __syncthreads();
    for (int off = 128; off > 0; off >>= 1) {
        if (threadIdx.x < off) s[threadIdx.x] += s[threadIdx.x + off];
        __syncthreads();
    }
    if (threadIdx.x == 0) bsum[blockIdx.x] = s[0];
}

__global__ void scan_bsums_kernel(int* __restrict__ bsum, int* __restrict__ row_ptr) {
    __shared__ int s[512];
    int t = threadIdx.x;
    int v = (t < NB_SCAN) ? bsum[t] : 0;
    s[t] = v; __syncthreads();
    for (int off = 1; off < 512; off <<= 1) {
        int x = (t >= off) ? s[t - off] : 0;
        __syncthreads();
        s[t] += x;
        __syncthreads();
    }
    if (t < NB_SCAN) bsum[t] = s[t] - v;              // exclusive
    if (t == NB_SCAN - 1) row_ptr[N_NODES] = s[t];    // total (= N_EDGES)
}

// also zeroes counts so it can be reused as the scatter fill array
__global__ void write_rowptr_kernel(int* __restrict__ counts, const int* __restrict__ bsum,
                                    int* __restrict__ row_ptr) {
    __shared__ int s[256];
    int i = blockIdx.x * 256 + threadIdx.x;
    int v = (i < N_NODES) ? counts[i] : 0;
    s[threadIdx.x] = v; __syncthreads();
    for (int off = 1; off < 256; off <<= 1) {
        int x = (threadIdx.x >= off) ? s[threadIdx.x - off] : 0;
        __syncthreads();
        s[threadIdx.x] += x;
        __syncthreads();
    }
    if (i < N_NODES) {
        row_ptr[i] = bsum[blockIdx.x] + s[threadIdx.x] - v;  // exclusive
        counts[i] = 0;                                       // becomes fill[]
    }
}

// pack (col, weight-bits) per sorted edge slot
__global__ void scatter_kernel(const int* __restrict__ rows, const int* __restrict__ cols,
                               const float* __restrict__ w, const int* __restrict__ row_ptr,
                               int* __restrict__ fill, int2* __restrict__ ecw) {
    int e = blockIdx.x * blockDim.x + threadIdx.x;
    if (e < N_EDGES) {
        int r = rows[e];
        r = min(max(r, 0), N_NODES - 1);
        int pos = row_ptr[r] + atomicAdd(&fill[r], 1);
        pos = min(max(pos, 0), N_EDGES - 1);
        int c = cols[e];
        c = min(max(c, 0), N_NODES - 1);
        ecw[pos] = make_int2(c, __float_as_int(w[e]));
    }
}

// -------- weight prep: W' = [W0-W2 | W1 | 2*W2], f32 -> bf16 ----------

__global__ void prep_w_kernel(const float* __restrict__ W, u16* __restrict__ Wp, int O) {
    int i = blockIdx.x * blockDim.x + threadIdx.x;
    if (i >= O * 384) return;
    int o = i / 384, k = i % 384;
    float v;
    if (k < 128)      v = W[o * 384 + k] - W[o * 384 + 256 + k];
    else if (k < 256) v = W[o * 384 + k];
    else              v = 2.0f * W[o * 384 + k];
    Wp[i] = f2bf(v);
}

// -------- x (f32) -> bf16, 4 elems per thread ----------

__global__ void cvt_kernel(const float* __restrict__ x, u16* __restrict__ y) {
    int i = blockIdx.x * blockDim.x + threadIdx.x;
    if (i >= N_NODES * FEAT / 4) return;
    float4 v = ((const float4*)x)[i];
    ushort4 o;
    o.x = f2bf(v.x); o.y = f2bf(v.y); o.z = f2bf(v.z); o.w = f2bf(v.w);
    ((ushort4*)y)[i] = o;
}

// -------- branch-free register gather, 4-row software pipeline -------------
// One wave computes 4 output rows. lane = g*16+f (g: edge slot in quad,
// f: feature group of 8). Per chunk: one clamped (branch-free) meta load,
// then NL=6 UNCONDITIONAL bf16x8 loads — pad lanes carry weight 0 via
// cndmask, so their (duplicate, L1-hot) loads contribute nothing.
// Rows are software-pipelined: row y+1's loads are issued before row y is
// reduced, keeping ~12 loads in flight per wave with zero exec-mask churn.

__device__ __forceinline__ void load_meta(const int2* __restrict__ ecw, int s, int n,
                                          int lane, int& call, float& wall) {
    int idx = s + max(0, min(lane, n - 1));       // clamp: branch-free
    idx = min(idx, N_EDGES - 1);
    int2 cw = ecw[idx];
    call = cw.x;
    wall = (lane < n) ? __int_as_float(cw.y) : 0.f;   // cndmask, no branch
}

__device__ __forceinline__ void issue_row(const u16* __restrict__ X, int call,
                                          int g, int f, bf16x8* q) {
#pragma unroll
    for (int k = 0; k < NL; ++k) {
        int col = __shfl(call, k * 4 + g);
        q[k] = *(const bf16x8*)(X + (size_t)col * FEAT + f * 8);
    }
}

__device__ __forceinline__ void reduce_row(const bf16x8* q, float wall,
                                           int g, float* acc) {
#pragma unroll
    for (int k = 0; k < NL; ++k) {
        float wj = __shfl(wall, k * 4 + g);
#pragma unroll
        for (int j = 0; j < 8; ++j) acc[j] += wj * bf2f((u16)q[k][j]);
    }
}

__device__ __forceinline__ void gather4(const int* __restrict__ row_ptr,
                                        const int2* __restrict__ ecw,
                                        const u16* __restrict__ X,
                                        int r0, int lane, int g, int f,
                                        float acc[4][8]) {
    int s[4], e[4];
    int call[4]; float wall[4];
#pragma unroll
    for (int y = 0; y < 4; ++y) {
        s[y] = row_ptr[r0 + y];
        e[y] = row_ptr[r0 + y + 1];
    }
#pragma unroll
    for (int y = 0; y < 4; ++y)
        load_meta(ecw, s[y], min(e[y] - s[y], CAP), lane, call[y], wall[y]);
#pragma unroll
    for (int y = 0; y < 4; ++y)
#pragma unroll
        for (int j = 0; j < 8; ++j) acc[y][j] = 0.f;

    bf16x8 q0[NL], q1[NL], q2[NL], q3[NL];
    issue_row(X, call[0], g, f, q0);
    issue_row(X, call[1], g, f, q1);
    reduce_row(q0, wall[0], g, acc[0]);
    issue_row(X, call[2], g, f, q2);
    reduce_row(q1, wall[1], g, acc[1]);
    issue_row(X, call[3], g, f, q3);
    reduce_row(q2, wall[2], g, acc[2]);
    reduce_row(q3, wall[3], g, acc[3]);

    // tail chunks (deg > CAP, ~1.7% of rows): branch-free body, uniform trip
#pragma unroll
    for (int y = 0; y < 4; ++y) {
        for (int cs = s[y] + CAP; cs < e[y]; cs += CAP) {
            int c2; float w2;
            load_meta(ecw, cs, min(e[y] - cs, CAP), lane, c2, w2);
            bf16x8 qt[NL];
            issue_row(X, c2, g, f, qt);
            reduce_row(qt, w2, g, acc[y]);
        }
    }

    // fold the 4 edge-slot groups: result replicated across g
#pragma unroll
    for (int y = 0; y < 4; ++y)
#pragma unroll
        for (int j = 0; j < 8; ++j) {
            acc[y][j] += __shfl_xor(acc[y][j], 16);
            acc[y][j] += __shfl_xor(acc[y][j], 32);
        }
}

// -------- SpMM: Y[r,:] = sum_e w_e * X[col_e,:]  (4 rows per wave) --------

__global__ __launch_bounds__(256) void spmm_kernel(const int* __restrict__ row_ptr,
                                                   const int2* __restrict__ ecw,
                                                   const u16* __restrict__ X,
                                                   u16* __restrict__ Y) {
    int wid = threadIdx.x >> 6;
    int lane = threadIdx.x & 63;
    int g = lane >> 4, f = lane & 15;
    int r0 = blockIdx.x * 16 + wid * 4;                   // 16 rows/block

    float acc[4][8];
    gather4(row_ptr, ecw, X, r0, lane, g, f, acc);

    if (g == 0) {
#pragma unroll
        for (int y = 0; y < 4; ++y) {
            u16 tmp[8];
#pragma unroll
            for (int j = 0; j < 8; ++j) tmp[j] = f2bf(acc[y][j]);
            *(bf16x8*)(Y + (size_t)(r0 + y) * FEAT + f * 8) = *(const bf16x8*)tmp;
        }
    }
}

// ------- fused: one block = one 16-row tile. Phase 1: 4 waves gather 4 s2
//         rows each into the shared sT tile. Phase 2: each wave computes O/64
//         column-tiles of out = act( H@W0' + T1@W1' + s2@W2' + b [+H] ).

template <int O, bool RELU, bool RES, bool OUT_F32>
__global__ __launch_bounds__(256) void fused_gemm_kernel(const int* __restrict__ row_ptr,
                                                         const int2* __restrict__ ecw,
                                                         const u16* __restrict__ H,
                                                         const u16* __restrict__ T1,
                                                         const u16* __restrict__ Wp,
                                                         const float* __restrict__ bias,
                                                         void* __restrict__ outv) {
    __shared__ __align__(16) u16 sT[16 * LDS_PITCH];      // 4.25 KB s2 tile
    int wid = threadIdx.x >> 6;
    int lane = threadIdx.x & 63;
    int g = lane >> 4, f = lane & 15;
    int m0 = blockIdx.x * 16;                             // N_NODES % 16 == 0

    // Phase 1: wave wid gathers s2 rows y = wid*4 .. wid*4+3
    {
        float acc[4][8];
        gather4(row_ptr, ecw, T1, m0 + wid * 4, lane, g, f, acc);
        if (g == 0) {
#pragma unroll
            for (int y = 0; y < 4; ++y) {
                u16 tmp[8];
#pragma unroll
                for (int j = 0; j < 8; ++j) tmp[j] = f2bf(acc[y][j]);
                *(bf16x8*)(sT + (wid * 4 + y) * LDS_PITCH + f * 8) = *(const bf16x8*)tmp;
            }
        }
    }
    __syncthreads();

    // Phase 2: MFMA over K = [H(128) | T1(128) | s2(128)]; wave wid owns
    // column-tiles t = wid*NW .. wid*NW+NW-1
    int r = f, q = g;
    constexpr int NT = O / 16;
    constexpr int NW = NT / 4;          // 2 for O=128, 1 for O=64
    f32x4 acc[NW];
#pragma unroll
    for (int t = 0; t < NW; ++t) acc[t] = (f32x4){0.f, 0.f, 0.f, 0.f};

#pragma unroll
    for (int kk = 0; kk < 12; ++kk) {
        bf16x8 af;
        if (kk < 4)
            af = *(const bf16x8*)(H + (size_t)(m0 + r) * FEAT + kk * 32 + q * 8);
        else if (kk < 8)
            af = *(const bf16x8*)(T1 + (size_t)(m0 + r) * FEAT + (kk - 4) * 32 + q * 8);
        else
            af = *(const bf16x8*)(sT + r * LDS_PITCH + (kk - 8) * 32 + q * 8);
#pragma unroll
        for (int t = 0; t < NW; ++t) {
            int ot = wid * NW + t;
            bf16x8 bfr = *(const bf16x8*)(Wp + (size_t)(ot * 16 + r) * 384 + kk * 32 + q * 8);
            acc[t] = __builtin_amdgcn_mfma_f32_16x16x32_bf16(af, bfr, acc[t], 0, 0, 0);
        }
    }

#pragma unroll
    for (int t = 0; t < NW; ++t) {
        int col = (wid * NW + t) * 16 + r;
        float bv = bias[col];
#pragma unroll
        for (int i = 0; i < 4; ++i) {
            int row = m0 + q * 4 + i;
            float v = acc[t][i] + bv;
            if (RES)  v += bf2f(H[(size_t)row * FEAT + col]);
            if (RELU) v = fmaxf(v, 0.f);
            if (OUT_F32) ((float*)outv)[(size_t)row * O + col] = v;
            else         ((u16*)outv)[(size_t)row * O + col] = f2bf(v);
        }
    }
}

// ---------------- launcher ----------------

static inline size_t align_up(size_t x) { return (x + 255) & ~(size_t)255; }

extern "C" void kernel_launch(void* const* d_in, const int* in_sizes, int n_in,
                              void* d_out, int out_size, void* d_ws, size_t ws_size,
                              hipStream_t stream) {
    const float* x     = (const float*)d_in[0];
    const int*   ei    = (const int*)d_in[1];
    const float* ew    = (const float*)d_in[2];
    const float* W_in  = (const float*)d_in[3];
    const float* b_in  = (const float*)d_in[4];
    const float* W_h1  = (const float*)d_in[5];
    const float* b_h1  = (const float*)d_in[6];
    const float* W_h2  = (const float*)d_in[7];
    const float* b_h2  = (const float*)d_in[8];
    const float* W_out = (const float*)d_in[9];
    const float* b_out = (const float*)d_in[10];

    const int* rows = ei;
    const int* cols = ei + N_EDGES;

    // workspace layout — ~65.2 MB (proven budget)
    char* w = (char*)d_ws;
    size_t off = 0;
    int* counts = (int*)(w + off);            off = align_up(off + (size_t)N_NODES * 4);   // reused as fill
    int* row_ptr= (int*)(w + off);            off = align_up(off + (size_t)(N_NODES + 1) * 4);
    int* bsum   = (int*)(w + off);            off = align_up(off + 512 * 4);
    int2* ecw   = (int2*)(w + off);           off = align_up(off + (size_t)N_EDGES * 8);
    u16* t1     = (u16*)(w + off);            off = align_up(off + (size_t)N_NODES * FEAT * 2);
    u16* h      = (u16*)(w + off);            off = align_up(off + (size_t)N_NODES * FEAT * 2);
    u16* Wp_in  = (u16*)(w + off);            off = align_up(off + (size_t)128 * 384 * 2);
    u16* Wp_h1  = (u16*)(w + off);            off = align_up(off + (size_t)128 * 384 * 2);
    u16* Wp_h2  = (u16*)(w + off);            off = align_up(off + (size_t)128 * 384 * 2);
    u16* Wp_out = (u16*)(w + off);            off = align_up(off + (size_t)64 * 384 * 2);

    hipMemsetAsync(counts, 0, (size_t)N_NODES * 4, stream);

    // weight prep + input conversion
    prep_w_kernel<<<(128 * 384 + 255) / 256, 256, 0, stream>>>(W_in, Wp_in, 128);
    prep_w_kernel<<<(128 * 384 + 255) / 256, 256, 0, stream>>>(W_h1, Wp_h1, 128);
    prep_w_kernel<<<(128 * 384 + 255) / 256, 256, 0, stream>>>(W_h2, Wp_h2, 128);
    prep_w_kernel<<<(64 * 384 + 255) / 256, 256, 0, stream>>>(W_out, Wp_out, 64);
    cvt_kernel<<<(N_NODES * FEAT / 4 + 255) / 256, 256, 0, stream>>>(x, h);

    // CSR build (counting sort)
    hist_kernel<<<N_EDGES / 256, 256, 0, stream>>>(rows, counts);
    reduce_counts_kernel<<<NB_SCAN, 256, 0, stream>>>(counts, bsum);
    scan_bsums_kernel<<<1, 512, 0, stream>>>(bsum, row_ptr);
    write_rowptr_kernel<<<NB_SCAN, 256, 0, stream>>>(counts, bsum, row_ptr);  // zeroes counts -> fill
    scatter_kernel<<<N_EDGES / 256, 256, 0, stream>>>(rows, cols, ew, row_ptr, counts, ecw);

    const int grid16 = N_NODES / 16;   // 6250 blocks: 16 rows per 256-thread block

    // Layer 1: h = relu(cheb(x))    (x pre-converted to bf16 in h; in-place row-local GEMM)
    spmm_kernel<<<grid16, 256, 0, stream>>>(row_ptr, ecw, h, t1);
    fused_gemm_kernel<128, true, false, false><<<grid16, 256, 0, stream>>>(
        row_ptr, ecw, h, t1, Wp_in, b_in, h);

    // Layer 2: h = relu(cheb(h) + h)
    spmm_kernel<<<grid16, 256, 0, stream>>>(row_ptr, ecw, h, t1);
    fused_gemm_kernel<128, true, true, false><<<grid16, 256, 0, stream>>>(
        row_ptr, ecw, h, t1, Wp_h1, b_h1, h);

    // Layer 3: h = relu(cheb(h) + h)
    spmm_kernel<<<grid16, 256, 0, stream>>>(row_ptr, ecw, h, t1);
    fused_gemm_kernel<128, true, true, false><<<grid16, 256, 0, stream>>>(
        row_ptr, ecw, h, t1, Wp_h2, b_h2, h);

    // Layer 4: out = cheb(h)   (O = 64, f32 output, no relu/residual)
    spmm_kernel<<<grid16, 256, 0, stream>>>(row_ptr, ecw, h, t1);
    fused_gemm_kernel<64, false, false, true><<<grid16, 256, 0, stream>>>(
        row_ptr, ecw, h, t1, Wp_out, b_out, d_out);
}